// Round 3
// baseline (958.973 us; speedup 1.0000x reference)
//
#include <hip/hip_runtime.h>
#include <hip/hip_bf16.h>
#include <math.h>

#define NL 4
#define DM 1024
#define DI 2048
#define RK 64
#define NS 16
#define LSEQ 1024
#define BATCH 2
#define MROWS (BATCH*LSEQ)   // 2048 rows for all GEMMs
#define NCHUNK 32
#define LC 32                // LSEQ / NCHUNK

typedef __attribute__((ext_vector_type(8))) short bf16x8;
typedef __attribute__((ext_vector_type(4))) float f32x4;

__device__ __forceinline__ float bf2f(unsigned short u){
  union { unsigned int i; float f; } v; v.i = ((unsigned int)u) << 16; return v.f;
}
__device__ __forceinline__ unsigned short f2bf(float f){
  union { float f; unsigned int i; } v; v.f = f;
  unsigned int r = v.i + 0x7fffu + ((v.i >> 16) & 1u);  // RNE
  return (unsigned short)(r >> 16);
}
__device__ __forceinline__ float sigmoidf_(float x){ return 1.0f / (1.0f + __expf(-x)); }
__device__ __forceinline__ float softplusf_(float x){ return (x > 20.0f) ? x : log1pf(__expf(x)); }

// async 16B/lane global->LDS DMA (lds dest = wave-uniform base + lane*16)
__device__ __forceinline__ void gl2lds16(const void* g, void* l) {
  __builtin_amdgcn_global_load_lds((__attribute__((address_space(1))) void*)g,
                                   (__attribute__((address_space(3))) void*)l,
                                   16, 0, 0);
}

// ---------------------------------------------------------------------------
// bf16 MFMA GEMM:  C[m,n] = sum_k A[m,k] * W[n,k]
// A row-major [M,K] bf16, W row-major [N,K] bf16 (B^T layout).
// BK=64 tile, global_load_lds staging with XOR bank-swizzle:
//   LDS 16B-unit j of tile row r holds global col-unit (j ^ (r&7)).
//   (DMA dest is lane-contiguous so the swizzle is applied to the GLOBAL
//    address per lane; readers un-swizzle -> conflict-free ds_read_b128.)
// EPI: 0 = store bf16; 2 = softplus(acc+bias[n]) fp32;
//      4 = store fp32 partial at slice blockIdx.z (split-K, no atomics)
// ---------------------------------------------------------------------------
template<int BM, int BN, int WAVES_M, int WAVES_N, int EPI>
__global__ __launch_bounds__(256)
void gemm_bt(const unsigned short* __restrict__ A, const unsigned short* __restrict__ W,
             void* __restrict__ C, const float* __restrict__ bias,
             int M, int N, int K, int ldc, int kslices)
{
  constexpr int MT = BM / (WAVES_M * 16);
  constexpr int NT = BN / (WAVES_N * 16);
  __shared__ __align__(16) unsigned short As[BM * 64];
  __shared__ __align__(16) unsigned short Bs[BN * 64];

  const int tid  = threadIdx.x;
  const int wave = tid >> 6;
  const int lane = tid & 63;
  const int wm   = wave / WAVES_N;
  const int wn   = wave % WAVES_N;
  const int quad = lane >> 4;
  const int l16  = lane & 15;
  const int srow = lane >> 3;              // row within 8-row staging chunk
  const int scol = ((lane & 7) ^ srow) * 8; // swizzled global col (bf16)

  const int m0 = blockIdx.x * BM;
  const int n0 = blockIdx.y * BN;
  const int Ks = K / kslices;
  const int kb = blockIdx.z * Ks;

  f32x4 acc[MT][NT];
  #pragma unroll
  for (int i = 0; i < MT; i++)
    #pragma unroll
    for (int j = 0; j < NT; j++)
      acc[i][j] = (f32x4){0.f, 0.f, 0.f, 0.f};

  for (int k0 = kb; k0 < kb + Ks; k0 += 64) {
    const unsigned short* Ab = A + (size_t)m0 * K + k0;
    #pragma unroll
    for (int i = 0; i < BM / 32; i++) {
      int c = i * 4 + wave;
      gl2lds16(Ab + (size_t)(c * 8 + srow) * K + scol, As + c * 512);
    }
    const unsigned short* Wb = W + (size_t)n0 * K + k0;
    #pragma unroll
    for (int i = 0; i < BN / 32; i++) {
      int c = i * 4 + wave;
      gl2lds16(Wb + (size_t)(c * 8 + srow) * K + scol, Bs + c * 512);
    }
    __syncthreads();

    #pragma unroll
    for (int h = 0; h < 2; h++) {
      bf16x8 af[MT], bfr[NT];
      #pragma unroll
      for (int mt = 0; mt < MT; mt++) {
        int rA = wm * MT * 16 + mt * 16 + l16;
        af[mt] = *(const bf16x8*)(As + rA * 64 + (((h * 4 + quad) ^ (rA & 7)) << 3));
      }
      #pragma unroll
      for (int nt = 0; nt < NT; nt++) {
        int rB = wn * NT * 16 + nt * 16 + l16;
        bfr[nt] = *(const bf16x8*)(Bs + rB * 64 + (((h * 4 + quad) ^ (rB & 7)) << 3));
      }
      #pragma unroll
      for (int mt = 0; mt < MT; mt++)
        #pragma unroll
        for (int nt = 0; nt < NT; nt++)
          acc[mt][nt] = __builtin_amdgcn_mfma_f32_16x16x32_bf16(af[mt], bfr[nt], acc[mt][nt], 0, 0, 0);
    }
    __syncthreads();
  }

  // epilogue: D[m][n] with m = quad*4 + r, n = l16 (verified gfx950 C/D layout)
  const size_t slice_off = (size_t)blockIdx.z * M * ldc;
  #pragma unroll
  for (int mt = 0; mt < MT; mt++) {
    #pragma unroll
    for (int nt = 0; nt < NT; nt++) {
      int n = n0 + wn * NT * 16 + nt * 16 + l16;
      #pragma unroll
      for (int r = 0; r < 4; r++) {
        int m = m0 + wm * MT * 16 + mt * 16 + quad * 4 + r;
        float v = acc[mt][nt][r];
        size_t off = (size_t)m * ldc + n;
        if constexpr (EPI == 0)      ((unsigned short*)C)[off] = f2bf(v);
        else if constexpr (EPI == 2) ((float*)C)[off] = softplusf_(v + bias[n]);
        else                         ((float*)C)[slice_off + off] = v;
      }
    }
  }
}

// x += sum of 4 split-K partials (GEMM4 epilogue)
__global__ __launch_bounds__(256)
void reduce4_kernel(const float* __restrict__ part, float* __restrict__ x)
{
  const size_t MN = (size_t)MROWS * DM;
  int i = blockIdx.x * 256 + threadIdx.x;
  float4 a = ((const float4*)part)[i];
  float4 b = ((const float4*)(part + MN))[i];
  float4 c = ((const float4*)(part + 2 * MN))[i];
  float4 d = ((const float4*)(part + 3 * MN))[i];
  float4 o = ((float4*)x)[i];
  o.x += a.x + b.x + c.x + d.x;
  o.y += a.y + b.y + c.y + d.y;
  o.z += a.z + b.z + c.z + d.z;
  o.w += a.w + b.w + c.w + d.w;
  ((float4*)x)[i] = o;
}

// dbc = sum of 4 split-K partials; also emit bf16 of cols 0..63 (dt for GEMM3)
__global__ __launch_bounds__(256)
void reduce2_kernel(const float* __restrict__ part, float* __restrict__ dbc,
                    unsigned short* __restrict__ dt_bf)
{
  const int MN = MROWS * 96;
  int i = blockIdx.x * 256 + threadIdx.x;
  float v = part[i] + part[MN + i] + part[2 * MN + i] + part[3 * MN + i];
  dbc[i] = v;
  int m = i / 96, c = i - m * 96;
  if (c < RK) dt_bf[m * RK + c] = f2bf(v);
}

// ---------------------------------------------------------------------------
__global__ __launch_bounds__(256)
void rmsnorm_kernel(const float* __restrict__ x, const float* __restrict__ w,
                    unsigned short* __restrict__ h)
{
  const int row = blockIdx.x;
  const float4 a = ((const float4*)(x + (size_t)row * DM))[threadIdx.x];
  float ss = a.x*a.x + a.y*a.y + a.z*a.z + a.w*a.w;
  #pragma unroll
  for (int o = 32; o > 0; o >>= 1) ss += __shfl_down(ss, o);
  __shared__ float red[4];
  if ((threadIdx.x & 63) == 0) red[threadIdx.x >> 6] = ss;
  __syncthreads();
  float rs = rsqrtf((red[0] + red[1] + red[2] + red[3]) * (1.0f / DM) + 1e-5f);
  const float4 wv = ((const float4*)w)[threadIdx.x];
  ushort4 o4;
  o4.x = f2bf(a.x * rs * wv.x);
  o4.y = f2bf(a.y * rs * wv.y);
  o4.z = f2bf(a.z * rs * wv.z);
  o4.w = f2bf(a.w * rs * wv.w);
  ((ushort4*)(h + (size_t)row * DM))[threadIdx.x] = o4;
}

// causal depthwise conv (width 4) + SiLU ; xi = xz[..., :DI]
__global__ __launch_bounds__(256)
void conv_silu_kernel(const unsigned short* __restrict__ xz,
                      const float* __restrict__ cw, const float* __restrict__ cb,
                      unsigned short* __restrict__ xc)
{
  int idx = blockIdx.x * 256 + threadIdx.x;        // [B, L, DI]
  int d = idx & (DI - 1);
  int t = (idx >> 11) & (LSEQ - 1);
  int b = idx >> 21;
  const float4 w4 = ((const float4*)cw)[d];
  const float wk[4] = {w4.x, w4.y, w4.z, w4.w};
  const unsigned short* xi = xz + (size_t)b * LSEQ * (2 * DI) + d;
  float acc = cb[d];
  #pragma unroll
  for (int k = 0; k < 4; k++) {
    int tt = t - 3 + k;
    if (tt >= 0) acc += bf2f(xi[(size_t)tt * (2 * DI)]) * wk[k];
  }
  xc[idx] = f2bf(acc * sigmoidf_(acc));
}

// one-shot fused fp32->bf16 conversion of all weights
__global__ void convert_all_kernel(const float* __restrict__ W_in, unsigned short* __restrict__ Win_bf,
                                   const float* __restrict__ W_x,  unsigned short* __restrict__ Wx_bf,
                                   const float* __restrict__ W_dt, unsigned short* __restrict__ Wdt_bf,
                                   const float* __restrict__ W_out,unsigned short* __restrict__ Wout_bf)
{
  const float* src[4]  = {W_in, W_x, W_dt, W_out};
  unsigned short* dst[4] = {Win_bf, Wx_bf, Wdt_bf, Wout_bf};
  const int n4[4] = {NL*2*DI*DM/4, NL*96*DI/4, NL*DI*RK/4, NL*DM*DI/4};
  for (int s = 0; s < 4; s++) {
    int stride = gridDim.x * 256;
    for (int i = blockIdx.x * 256 + threadIdx.x; i < n4[s]; i += stride) {
      float4 v = ((const float4*)src[s])[i];
      ushort4 o; o.x = f2bf(v.x); o.y = f2bf(v.y); o.z = f2bf(v.z); o.w = f2bf(v.w);
      ((ushort4*)dst[s])[i] = o;
    }
  }
}

// ---------------------------------------------------------------------------
// Chunked selective scan.  State layout for hend/hin: [b][chunk][n][d] (coalesced in d)
// ---------------------------------------------------------------------------
__global__ __launch_bounds__(256)
void scan1_kernel(const float* __restrict__ delta, const unsigned short* __restrict__ xc,
                  const float* __restrict__ dbc, const float* __restrict__ A_log,
                  float* __restrict__ hend, float* __restrict__ sumd)
{
  const int d = blockIdx.x * 256 + threadIdx.x;
  const int c = blockIdx.y;
  const int b = blockIdx.z;
  const int t0 = c * LC;
  __shared__ float bc[LC][32];                     // cols 0..15 = B, 16..31 = C
  #pragma unroll
  for (int i = 0; i < (LC * 32) / 256; i++) {
    int f = i * 256 + threadIdx.x;
    int r = f >> 5, col = f & 31;
    bc[r][col] = dbc[(size_t)(b * LSEQ + t0 + r) * 96 + 64 + col];
  }
  float Av[NS], h[NS];
  #pragma unroll
  for (int n = 0; n < NS; n++) { Av[n] = -__expf(A_log[(size_t)d * NS + n]); h[n] = 0.f; }
  __syncthreads();
  float sd = 0.f;
  for (int t = 0; t < LC; t++) {
    size_t ix = (size_t)(b * LSEQ + t0 + t) * DI + d;
    float dt = delta[ix];
    float xcv = bf2f(xc[ix]);
    sd += dt;
    float dx = dt * xcv;
    #pragma unroll
    for (int n = 0; n < NS; n++) {
      float da = __expf(dt * Av[n]);
      h[n] = da * h[n] + dx * bc[t][n];
    }
  }
  size_t base = ((size_t)(b * NCHUNK + c) * NS) * DI + d;
  #pragma unroll
  for (int n = 0; n < NS; n++) hend[base + (size_t)n * DI] = h[n];
  sumd[(size_t)(b * NCHUNK + c) * DI + d] = sd;
}

__global__ __launch_bounds__(256)
void scan2_kernel(const float* __restrict__ A_log, const float* __restrict__ hend,
                  const float* __restrict__ sumd, float* __restrict__ hin)
{
  int g = blockIdx.x * 256 + threadIdx.x;          // BATCH*DI threads
  int b = g >> 11;
  int d = g & (DI - 1);
  float Av[NS], H[NS];
  #pragma unroll
  for (int n = 0; n < NS; n++) { Av[n] = -__expf(A_log[(size_t)d * NS + n]); H[n] = 0.f; }
  for (int c = 0; c < NCHUNK; c++) {
    size_t base = ((size_t)(b * NCHUNK + c) * NS) * DI + d;
    float sd = sumd[(size_t)(b * NCHUNK + c) * DI + d];
    #pragma unroll
    for (int n = 0; n < NS; n++) {
      hin[base + (size_t)n * DI] = H[n];
      float da = __expf(Av[n] * sd);
      H[n] = da * H[n] + hend[base + (size_t)n * DI];
    }
  }
}

__global__ __launch_bounds__(256)
void scan3_kernel(const float* __restrict__ delta, const unsigned short* __restrict__ xc,
                  const float* __restrict__ dbc, const float* __restrict__ A_log,
                  const float* __restrict__ hin, const float* __restrict__ Dvec,
                  const unsigned short* __restrict__ xz, unsigned short* __restrict__ g)
{
  const int d = blockIdx.x * 256 + threadIdx.x;
  const int c = blockIdx.y;
  const int b = blockIdx.z;
  const int t0 = c * LC;
  __shared__ float bc[LC][32];
  #pragma unroll
  for (int i = 0; i < (LC * 32) / 256; i++) {
    int f = i * 256 + threadIdx.x;
    int r = f >> 5, col = f & 31;
    bc[r][col] = dbc[(size_t)(b * LSEQ + t0 + r) * 96 + 64 + col];
  }
  float Av[NS], h[NS];
  size_t base = ((size_t)(b * NCHUNK + c) * NS) * DI + d;
  #pragma unroll
  for (int n = 0; n < NS; n++) {
    Av[n] = -__expf(A_log[(size_t)d * NS + n]);
    h[n] = hin[base + (size_t)n * DI];
  }
  const float Dd = Dvec[d];
  __syncthreads();
  for (int t = 0; t < LC; t++) {
    size_t ix = (size_t)(b * LSEQ + t0 + t) * DI + d;
    float dt = delta[ix];
    float xcv = bf2f(xc[ix]);
    float dx = dt * xcv;
    float y = Dd * xcv;
    #pragma unroll
    for (int n = 0; n < NS; n++) {
      float da = __expf(dt * Av[n]);
      h[n] = da * h[n] + dx * bc[t][n];
      y += h[n] * bc[t][16 + n];
    }
    float zv = bf2f(xz[(size_t)(b * LSEQ + t0 + t) * (2 * DI) + DI + d]);
    g[ix] = f2bf(y * (zv * sigmoidf_(zv)));
  }
}

// ---------------------------------------------------------------------------
extern "C" void kernel_launch(void* const* d_in, const int* in_sizes, int n_in,
                              void* d_out, int out_size, void* d_ws, size_t ws_size,
                              hipStream_t stream)
{
  const float* x_in   = (const float*)d_in[0];
  const float* norm_w = (const float*)d_in[1];
  const float* W_in   = (const float*)d_in[2];
  const float* conv_w = (const float*)d_in[3];
  const float* conv_b = (const float*)d_in[4];
  const float* W_x    = (const float*)d_in[5];
  const float* W_dt   = (const float*)d_in[6];
  const float* b_dt   = (const float*)d_in[7];
  const float* A_log  = (const float*)d_in[8];
  const float* Dv     = (const float*)d_in[9];
  const float* W_out  = (const float*)d_in[10];
  float* x = (float*)d_out;                        // running residual stream

  char* p = (char*)d_ws;
  auto alloc = [&](size_t bytes) {
    void* r = (void*)p;
    p += (bytes + 255) & ~(size_t)255;
    return r;
  };
  unsigned short* Win_bf  = (unsigned short*)alloc((size_t)NL * 2 * DI * DM * 2);
  unsigned short* Wx_bf   = (unsigned short*)alloc((size_t)NL * 96 * DI * 2);
  unsigned short* Wdt_bf  = (unsigned short*)alloc((size_t)NL * DI * RK * 2);
  unsigned short* Wout_bf = (unsigned short*)alloc((size_t)NL * DM * DI * 2);
  unsigned short* h_bf    = (unsigned short*)alloc((size_t)MROWS * DM * 2);
  unsigned short* xz_bf   = (unsigned short*)alloc((size_t)MROWS * 2 * DI * 2);
  unsigned short* xc_bf   = (unsigned short*)alloc((size_t)MROWS * DI * 2);
  float*          dbc     = (float*)alloc((size_t)MROWS * 96 * 4);
  unsigned short* dt_bf   = (unsigned short*)alloc((size_t)MROWS * RK * 2);
  unsigned short* g_bf    = (unsigned short*)alloc((size_t)MROWS * DI * 2);
  float*          delta   = (float*)alloc((size_t)MROWS * DI * 4);
  float*          hend    = (float*)alloc((size_t)BATCH * NCHUNK * NS * DI * 4);
  float*          hin     = (float*)alloc((size_t)BATCH * NCHUNK * NS * DI * 4);
  float*          sumd    = (float*)alloc((size_t)BATCH * NCHUNK * DI * 4);
  // split-K partials alias the delta..sumd region (dead at their use time):
  //  part2 (3 MB)  live GEMM2->reduce2, before GEMM3 writes delta
  //  part4 (32 MB) live GEMM4->reduce4, after scan3 is done with delta/hend/hin
  float* part2 = delta;
  float* part4 = delta;

  hipMemcpyAsync(x, x_in, (size_t)MROWS * DM * 4, hipMemcpyDeviceToDevice, stream);

  convert_all_kernel<<<2048, 256, 0, stream>>>(W_in, Win_bf, W_x, Wx_bf,
                                               W_dt, Wdt_bf, W_out, Wout_bf);

  for (int l = 0; l < NL; l++) {
    const unsigned short* Win_l  = Win_bf  + (size_t)l * 2 * DI * DM;
    const unsigned short* Wx_l   = Wx_bf   + (size_t)l * 96 * DI;
    const unsigned short* Wdt_l  = Wdt_bf  + (size_t)l * DI * RK;
    const unsigned short* Wout_l = Wout_bf + (size_t)l * DM * DI;

    rmsnorm_kernel<<<MROWS, 256, 0, stream>>>(x, norm_w + (size_t)l * DM, h_bf);

    // GEMM1: xz = h @ W_in^T   [2048, 4096], K=1024  -> bf16
    gemm_bt<128, 128, 2, 2, 0><<<dim3(MROWS / 128, (2 * DI) / 128), 256, 0, stream>>>(
        h_bf, Win_l, xz_bf, nullptr, MROWS, 2 * DI, DM, 2 * DI, 1);

    conv_silu_kernel<<<(BATCH * LSEQ * DI) / 256, 256, 0, stream>>>(
        xz_bf, conv_w + (size_t)l * DI * 4, conv_b + (size_t)l * DI, xc_bf);

    // GEMM2: dbc = xc @ W_x^T  [2048, 96], K=2048, split-K=4 -> partials
    gemm_bt<64, 96, 4, 1, 4><<<dim3(MROWS / 64, 1, 4), 256, 0, stream>>>(
        xc_bf, Wx_l, part2, nullptr, MROWS, 96, DI, 96, 4);
    reduce2_kernel<<<(MROWS * 96) / 256, 256, 0, stream>>>(part2, dbc, dt_bf);

    // GEMM3: delta = softplus(dbc[:, :64] @ W_dt^T + b_dt)  [2048, 2048], K=64
    gemm_bt<128, 128, 2, 2, 2><<<dim3(MROWS / 128, DI / 128), 256, 0, stream>>>(
        dt_bf, Wdt_l, delta, b_dt + (size_t)l * DI, MROWS, DI, RK, DI, 1);

    // selective scan (chunked 3-phase)
    scan1_kernel<<<dim3(DI / 256, NCHUNK, BATCH), 256, 0, stream>>>(
        delta, xc_bf, dbc, A_log + (size_t)l * DI * NS, hend, sumd);
    scan2_kernel<<<(BATCH * DI) / 256, 256, 0, stream>>>(
        A_log + (size_t)l * DI * NS, hend, sumd, hin);
    scan3_kernel<<<dim3(DI / 256, NCHUNK, BATCH), 256, 0, stream>>>(
        delta, xc_bf, dbc, A_log + (size_t)l * DI * NS, hin, Dv + (size_t)l * DI, xz_bf, g_bf);

    // GEMM4: split-K=4 partials of (y*silu(z)) @ W_out^T, then x += sum(parts)
    gemm_bt<128, 128, 2, 2, 4><<<dim3(MROWS / 128, DM / 128, 4), 256, 0, stream>>>(
        g_bf, Wout_l, part4, nullptr, MROWS, DM, DI, DM, 4);
    reduce4_kernel<<<(MROWS * DM) / 1024, 256, 0, stream>>>(part4, x);
  }
}

// Round 4
// 851.507 us; speedup vs baseline: 1.1262x; 1.1262x over previous
//
#include <hip/hip_runtime.h>
#include <hip/hip_bf16.h>
#include <math.h>

#define NL 4
#define DM 1024
#define DI 2048
#define RK 64
#define NS 16
#define LSEQ 1024
#define BATCH 2
#define MROWS (BATCH*LSEQ)   // 2048 rows for all GEMMs
#define NCHUNK 32
#define LC 32                // LSEQ / NCHUNK

typedef __attribute__((ext_vector_type(8))) short bf16x8;
typedef __attribute__((ext_vector_type(4))) float f32x4;

__device__ __forceinline__ float bf2f(unsigned short u){
  union { unsigned int i; float f; } v; v.i = ((unsigned int)u) << 16; return v.f;
}
__device__ __forceinline__ unsigned short f2bf(float f){
  union { float f; unsigned int i; } v; v.f = f;
  unsigned int r = v.i + 0x7fffu + ((v.i >> 16) & 1u);  // RNE
  return (unsigned short)(r >> 16);
}
__device__ __forceinline__ float sigmoidf_(float x){ return 1.0f / (1.0f + __expf(-x)); }
__device__ __forceinline__ float softplusf_(float x){ return (x > 20.0f) ? x : log1pf(__expf(x)); }

// async 16B/lane global->LDS DMA (lds dest = wave-uniform base + lane*16)
__device__ __forceinline__ void gl2lds16(const void* g, void* l) {
  __builtin_amdgcn_global_load_lds((__attribute__((address_space(1))) void*)g,
                                   (__attribute__((address_space(3))) void*)l,
                                   16, 0, 0);
}

// ---------------------------------------------------------------------------
// bf16 MFMA GEMM:  C[m,n] = sum_k A[m,k] * W[n,k]
// A row-major [M,K] bf16, W row-major [N,K] bf16 (B^T layout).
// BK=64 tile, global_load_lds staging with XOR bank-swizzle:
//   LDS 16B-unit j of tile row r holds global col-unit (j ^ (r&7)).
// EPI: 0 = store bf16; 4 = store fp32 partial at slice blockIdx.z (split-K)
// ---------------------------------------------------------------------------
template<int BM, int BN, int WAVES_M, int WAVES_N, int EPI>
__global__ __launch_bounds__(256)
void gemm_bt(const unsigned short* __restrict__ A, const unsigned short* __restrict__ W,
             void* __restrict__ C, const float* __restrict__ bias,
             int M, int N, int K, int ldc, int kslices)
{
  constexpr int MT = BM / (WAVES_M * 16);
  constexpr int NT = BN / (WAVES_N * 16);
  __shared__ __align__(16) unsigned short As[BM * 64];
  __shared__ __align__(16) unsigned short Bs[BN * 64];

  const int tid  = threadIdx.x;
  const int wave = tid >> 6;
  const int lane = tid & 63;
  const int wm   = wave / WAVES_N;
  const int wn   = wave % WAVES_N;
  const int quad = lane >> 4;
  const int l16  = lane & 15;
  const int srow = lane >> 3;               // row within 8-row staging chunk
  const int scol = ((lane & 7) ^ srow) * 8; // swizzled global col (bf16)

  const int m0 = blockIdx.x * BM;
  const int n0 = blockIdx.y * BN;
  const int Ks = K / kslices;
  const int kb = blockIdx.z * Ks;

  f32x4 acc[MT][NT];
  #pragma unroll
  for (int i = 0; i < MT; i++)
    #pragma unroll
    for (int j = 0; j < NT; j++)
      acc[i][j] = (f32x4){0.f, 0.f, 0.f, 0.f};

  for (int k0 = kb; k0 < kb + Ks; k0 += 64) {
    const unsigned short* Ab = A + (size_t)m0 * K + k0;
    #pragma unroll
    for (int i = 0; i < BM / 32; i++) {
      int c = i * 4 + wave;
      gl2lds16(Ab + (size_t)(c * 8 + srow) * K + scol, As + c * 512);
    }
    const unsigned short* Wb = W + (size_t)n0 * K + k0;
    #pragma unroll
    for (int i = 0; i < BN / 32; i++) {
      int c = i * 4 + wave;
      gl2lds16(Wb + (size_t)(c * 8 + srow) * K + scol, Bs + c * 512);
    }
    __syncthreads();

    #pragma unroll
    for (int h = 0; h < 2; h++) {
      bf16x8 af[MT], bfr[NT];
      #pragma unroll
      for (int mt = 0; mt < MT; mt++) {
        int rA = wm * MT * 16 + mt * 16 + l16;
        af[mt] = *(const bf16x8*)(As + rA * 64 + (((h * 4 + quad) ^ (rA & 7)) << 3));
      }
      #pragma unroll
      for (int nt = 0; nt < NT; nt++) {
        int rB = wn * NT * 16 + nt * 16 + l16;
        bfr[nt] = *(const bf16x8*)(Bs + rB * 64 + (((h * 4 + quad) ^ (rB & 7)) << 3));
      }
      #pragma unroll
      for (int mt = 0; mt < MT; mt++)
        #pragma unroll
        for (int nt = 0; nt < NT; nt++)
          acc[mt][nt] = __builtin_amdgcn_mfma_f32_16x16x32_bf16(af[mt], bfr[nt], acc[mt][nt], 0, 0, 0);
    }
    __syncthreads();
  }

  // epilogue: D[m][n] with m = quad*4 + r, n = l16 (verified gfx950 C/D layout)
  const size_t slice_off = (size_t)blockIdx.z * M * ldc;
  #pragma unroll
  for (int mt = 0; mt < MT; mt++) {
    #pragma unroll
    for (int nt = 0; nt < NT; nt++) {
      int n = n0 + wn * NT * 16 + nt * 16 + l16;
      #pragma unroll
      for (int r = 0; r < 4; r++) {
        int m = m0 + wm * MT * 16 + mt * 16 + quad * 4 + r;
        float v = acc[mt][nt][r];
        size_t off = (size_t)m * ldc + n;
        if constexpr (EPI == 0)      ((unsigned short*)C)[off] = f2bf(v);
        else                         ((float*)C)[slice_off + off] = v;
      }
    }
  }
}

// ---------------------------------------------------------------------------
// GEMM3 replacement (K=64, 0.5 GFLOP -> pure VALU):
//   delta[m, c] = softplus( dot(dbc[m, 0:64], Wdt[c, 0:64]) + b_dt[c] )
// Block: 8 rows x 256 cols, 2048 blocks (8/CU). dbc rows staged fp32 in LDS;
// Wdt tile staged TRANSPOSED in LDS (row stride 264 shorts = 528 B, 16B-aligned
// -> conflict-free ds_read_b128). Each thread: 8 outputs, 512 FMAs.
// ---------------------------------------------------------------------------
#define G3R 8
#define G3C 256
#define G3P 264   // padded LDS row stride (shorts)
__global__ __launch_bounds__(256)
void gemm3_fused(const float* __restrict__ dbc, const unsigned short* __restrict__ Wdt,
                 const float* __restrict__ b_dt, float* __restrict__ delta)
{
  __shared__ float dts[G3R][RK];                       // 2 KB
  __shared__ __align__(16) unsigned short Ws[RK][G3P]; // ~33 KB, [k][col]
  const int tid = threadIdx.x;
  const int m0 = blockIdx.x * G3R;
  const int c0 = blockIdx.y * G3C;

  { // stage dbc rows (first 64 cols of the 96-col rows)
    int r = tid >> 5, k = (tid & 31) * 2;
    float2 v = *(const float2*)(dbc + (size_t)(m0 + r) * 96 + k);
    dts[r][k] = v.x; dts[r][k + 1] = v.y;
  }
  { // stage Wdt[c0+tid][0:64] transposed into Ws[k][tid]
    const unsigned short* wrow = Wdt + (size_t)(c0 + tid) * RK;
    #pragma unroll
    for (int ch = 0; ch < 8; ch++) {
      union { bf16x8 v; unsigned short u[8]; } w;
      w.v = *(const bf16x8*)(wrow + ch * 8);
      #pragma unroll
      for (int j = 0; j < 8; j++) Ws[ch * 8 + j][tid] = w.u[j];
    }
  }
  __syncthreads();

  const int r  = tid >> 5;       // row within block
  const int cg = tid & 31;       // 8-col group
  float acc[8] = {0.f, 0.f, 0.f, 0.f, 0.f, 0.f, 0.f, 0.f};
  #pragma unroll 4
  for (int k = 0; k < RK; k++) {
    float a = dts[r][k];
    union { bf16x8 v; unsigned short u[8]; } w;
    w.v = *(const bf16x8*)&Ws[k][cg * 8];
    #pragma unroll
    for (int j = 0; j < 8; j++) acc[j] += a * bf2f(w.u[j]);
  }

  const int m = m0 + r, c = c0 + cg * 8;
  float4 b0 = *(const float4*)(b_dt + c);
  float4 b1 = *(const float4*)(b_dt + c + 4);
  float bb[8] = {b0.x, b0.y, b0.z, b0.w, b1.x, b1.y, b1.z, b1.w};
  float out[8];
  #pragma unroll
  for (int j = 0; j < 8; j++) {
    float v = acc[j] + bb[j];
    out[j] = (v > 15.0f) ? v : __logf(1.0f + __expf(v));
  }
  float* dp = delta + (size_t)m * DI + c;
  *(float4*)dp       = (float4){out[0], out[1], out[2], out[3]};
  *(float4*)(dp + 4) = (float4){out[4], out[5], out[6], out[7]};
}

// x += sum of 4 split-K partials (GEMM4 epilogue)
__global__ __launch_bounds__(256)
void reduce4_kernel(const float* __restrict__ part, float* __restrict__ x)
{
  const size_t MN = (size_t)MROWS * DM;
  int i = blockIdx.x * 256 + threadIdx.x;
  float4 a = ((const float4*)part)[i];
  float4 b = ((const float4*)(part + MN))[i];
  float4 c = ((const float4*)(part + 2 * MN))[i];
  float4 d = ((const float4*)(part + 3 * MN))[i];
  float4 o = ((float4*)x)[i];
  o.x += a.x + b.x + c.x + d.x;
  o.y += a.y + b.y + c.y + d.y;
  o.z += a.z + b.z + c.z + d.z;
  o.w += a.w + b.w + c.w + d.w;
  ((float4*)x)[i] = o;
}

// dbc = sum of 4 split-K partials
__global__ __launch_bounds__(256)
void reduce2_kernel(const float* __restrict__ part, float* __restrict__ dbc)
{
  const int MN = MROWS * 96;
  int i = blockIdx.x * 256 + threadIdx.x;
  dbc[i] = part[i] + part[MN + i] + part[2 * MN + i] + part[3 * MN + i];
}

// ---------------------------------------------------------------------------
__global__ __launch_bounds__(256)
void rmsnorm_kernel(const float* __restrict__ x, const float* __restrict__ w,
                    unsigned short* __restrict__ h)
{
  const int row = blockIdx.x;
  const float4 a = ((const float4*)(x + (size_t)row * DM))[threadIdx.x];
  float ss = a.x*a.x + a.y*a.y + a.z*a.z + a.w*a.w;
  #pragma unroll
  for (int o = 32; o > 0; o >>= 1) ss += __shfl_down(ss, o);
  __shared__ float red[4];
  if ((threadIdx.x & 63) == 0) red[threadIdx.x >> 6] = ss;
  __syncthreads();
  float rs = rsqrtf((red[0] + red[1] + red[2] + red[3]) * (1.0f / DM) + 1e-5f);
  const float4 wv = ((const float4*)w)[threadIdx.x];
  ushort4 o4;
  o4.x = f2bf(a.x * rs * wv.x);
  o4.y = f2bf(a.y * rs * wv.y);
  o4.z = f2bf(a.z * rs * wv.z);
  o4.w = f2bf(a.w * rs * wv.w);
  ((ushort4*)(h + (size_t)row * DM))[threadIdx.x] = o4;
}

// causal depthwise conv (width 4) + SiLU ; xi = xz[..., :DI]
__global__ __launch_bounds__(256)
void conv_silu_kernel(const unsigned short* __restrict__ xz,
                      const float* __restrict__ cw, const float* __restrict__ cb,
                      unsigned short* __restrict__ xc)
{
  int idx = blockIdx.x * 256 + threadIdx.x;        // [B, L, DI]
  int d = idx & (DI - 1);
  int t = (idx >> 11) & (LSEQ - 1);
  int b = idx >> 21;
  const float4 w4 = ((const float4*)cw)[d];
  const float wk[4] = {w4.x, w4.y, w4.z, w4.w};
  const unsigned short* xi = xz + (size_t)b * LSEQ * (2 * DI) + d;
  float acc = cb[d];
  #pragma unroll
  for (int k = 0; k < 4; k++) {
    int tt = t - 3 + k;
    if (tt >= 0) acc += bf2f(xi[(size_t)tt * (2 * DI)]) * wk[k];
  }
  xc[idx] = f2bf(acc * sigmoidf_(acc));
}

// one-shot fused fp32->bf16 conversion of all weights
__global__ void convert_all_kernel(const float* __restrict__ W_in, unsigned short* __restrict__ Win_bf,
                                   const float* __restrict__ W_x,  unsigned short* __restrict__ Wx_bf,
                                   const float* __restrict__ W_dt, unsigned short* __restrict__ Wdt_bf,
                                   const float* __restrict__ W_out,unsigned short* __restrict__ Wout_bf)
{
  const float* src[4]  = {W_in, W_x, W_dt, W_out};
  unsigned short* dst[4] = {Win_bf, Wx_bf, Wdt_bf, Wout_bf};
  const int n4[4] = {NL*2*DI*DM/4, NL*96*DI/4, NL*DI*RK/4, NL*DM*DI/4};
  for (int s = 0; s < 4; s++) {
    int stride = gridDim.x * 256;
    for (int i = blockIdx.x * 256 + threadIdx.x; i < n4[s]; i += stride) {
      float4 v = ((const float4*)src[s])[i];
      ushort4 o; o.x = f2bf(v.x); o.y = f2bf(v.y); o.z = f2bf(v.z); o.w = f2bf(v.w);
      ((ushort4*)dst[s])[i] = o;
    }
  }
}

// ---------------------------------------------------------------------------
// Chunked selective scan.  State layout for hend/hin: [b][chunk][n][d] (coalesced in d)
// ---------------------------------------------------------------------------
__global__ __launch_bounds__(256)
void scan1_kernel(const float* __restrict__ delta, const unsigned short* __restrict__ xc,
                  const float* __restrict__ dbc, const float* __restrict__ A_log,
                  float* __restrict__ hend, float* __restrict__ sumd)
{
  const int d = blockIdx.x * 256 + threadIdx.x;
  const int c = blockIdx.y;
  const int b = blockIdx.z;
  const int t0 = c * LC;
  __shared__ float bc[LC][32];                     // cols 0..15 = B, 16..31 = C
  #pragma unroll
  for (int i = 0; i < (LC * 32) / 256; i++) {
    int f = i * 256 + threadIdx.x;
    int r = f >> 5, col = f & 31;
    bc[r][col] = dbc[(size_t)(b * LSEQ + t0 + r) * 96 + 64 + col];
  }
  float Av[NS], h[NS];
  #pragma unroll
  for (int n = 0; n < NS; n++) { Av[n] = -__expf(A_log[(size_t)d * NS + n]); h[n] = 0.f; }
  __syncthreads();
  float sd = 0.f;
  for (int t = 0; t < LC; t++) {
    size_t ix = (size_t)(b * LSEQ + t0 + t) * DI + d;
    float dt = delta[ix];
    float xcv = bf2f(xc[ix]);
    sd += dt;
    float dx = dt * xcv;
    #pragma unroll
    for (int n = 0; n < NS; n++) {
      float da = __expf(dt * Av[n]);
      h[n] = da * h[n] + dx * bc[t][n];
    }
  }
  size_t base = ((size_t)(b * NCHUNK + c) * NS) * DI + d;
  #pragma unroll
  for (int n = 0; n < NS; n++) hend[base + (size_t)n * DI] = h[n];
  sumd[(size_t)(b * NCHUNK + c) * DI + d] = sd;
}

__global__ __launch_bounds__(256)
void scan2_kernel(const float* __restrict__ A_log, const float* __restrict__ hend,
                  const float* __restrict__ sumd, float* __restrict__ hin)
{
  int g = blockIdx.x * 256 + threadIdx.x;          // BATCH*DI threads
  int b = g >> 11;
  int d = g & (DI - 1);
  float Av[NS], H[NS];
  #pragma unroll
  for (int n = 0; n < NS; n++) { Av[n] = -__expf(A_log[(size_t)d * NS + n]); H[n] = 0.f; }
  for (int c = 0; c < NCHUNK; c++) {
    size_t base = ((size_t)(b * NCHUNK + c) * NS) * DI + d;
    float sd = sumd[(size_t)(b * NCHUNK + c) * DI + d];
    #pragma unroll
    for (int n = 0; n < NS; n++) {
      hin[base + (size_t)n * DI] = H[n];
      float da = __expf(Av[n] * sd);
      H[n] = da * H[n] + hend[base + (size_t)n * DI];
    }
  }
}

__global__ __launch_bounds__(256)
void scan3_kernel(const float* __restrict__ delta, const unsigned short* __restrict__ xc,
                  const float* __restrict__ dbc, const float* __restrict__ A_log,
                  const float* __restrict__ hin, const float* __restrict__ Dvec,
                  const unsigned short* __restrict__ xz, unsigned short* __restrict__ g)
{
  const int d = blockIdx.x * 256 + threadIdx.x;
  const int c = blockIdx.y;
  const int b = blockIdx.z;
  const int t0 = c * LC;
  __shared__ float bc[LC][32];
  #pragma unroll
  for (int i = 0; i < (LC * 32) / 256; i++) {
    int f = i * 256 + threadIdx.x;
    int r = f >> 5, col = f & 31;
    bc[r][col] = dbc[(size_t)(b * LSEQ + t0 + r) * 96 + 64 + col];
  }
  float Av[NS], h[NS];
  size_t base = ((size_t)(b * NCHUNK + c) * NS) * DI + d;
  #pragma unroll
  for (int n = 0; n < NS; n++) {
    Av[n] = -__expf(A_log[(size_t)d * NS + n]);
    h[n] = hin[base + (size_t)n * DI];
  }
  const float Dd = Dvec[d];
  __syncthreads();
  for (int t = 0; t < LC; t++) {
    size_t ix = (size_t)(b * LSEQ + t0 + t) * DI + d;
    float dt = delta[ix];
    float xcv = bf2f(xc[ix]);
    float dx = dt * xcv;
    float y = Dd * xcv;
    #pragma unroll
    for (int n = 0; n < NS; n++) {
      float da = __expf(dt * Av[n]);
      h[n] = da * h[n] + dx * bc[t][n];
      y += h[n] * bc[t][16 + n];
    }
    float zv = bf2f(xz[(size_t)(b * LSEQ + t0 + t) * (2 * DI) + DI + d]);
    g[ix] = f2bf(y * (zv * sigmoidf_(zv)));
  }
}

// ---------------------------------------------------------------------------
extern "C" void kernel_launch(void* const* d_in, const int* in_sizes, int n_in,
                              void* d_out, int out_size, void* d_ws, size_t ws_size,
                              hipStream_t stream)
{
  const float* x_in   = (const float*)d_in[0];
  const float* norm_w = (const float*)d_in[1];
  const float* W_in   = (const float*)d_in[2];
  const float* conv_w = (const float*)d_in[3];
  const float* conv_b = (const float*)d_in[4];
  const float* W_x    = (const float*)d_in[5];
  const float* W_dt   = (const float*)d_in[6];
  const float* b_dt   = (const float*)d_in[7];
  const float* A_log  = (const float*)d_in[8];
  const float* Dv     = (const float*)d_in[9];
  const float* W_out  = (const float*)d_in[10];
  float* x = (float*)d_out;                        // running residual stream

  char* p = (char*)d_ws;
  auto alloc = [&](size_t bytes) {
    void* r = (void*)p;
    p += (bytes + 255) & ~(size_t)255;
    return r;
  };
  unsigned short* Win_bf  = (unsigned short*)alloc((size_t)NL * 2 * DI * DM * 2);
  unsigned short* Wx_bf   = (unsigned short*)alloc((size_t)NL * 96 * DI * 2);
  unsigned short* Wdt_bf  = (unsigned short*)alloc((size_t)NL * DI * RK * 2);
  unsigned short* Wout_bf = (unsigned short*)alloc((size_t)NL * DM * DI * 2);
  unsigned short* h_bf    = (unsigned short*)alloc((size_t)MROWS * DM * 2);
  unsigned short* xz_bf   = (unsigned short*)alloc((size_t)MROWS * 2 * DI * 2);
  unsigned short* xc_bf   = (unsigned short*)alloc((size_t)MROWS * DI * 2);
  float*          dbc     = (float*)alloc((size_t)MROWS * 96 * 4);
  unsigned short* g_bf    = (unsigned short*)alloc((size_t)MROWS * DI * 2);
  float*          delta   = (float*)alloc((size_t)MROWS * DI * 4);
  float*          hend    = (float*)alloc((size_t)BATCH * NCHUNK * NS * DI * 4);
  float*          hin     = (float*)alloc((size_t)BATCH * NCHUNK * NS * DI * 4);
  float*          sumd    = (float*)alloc((size_t)BATCH * NCHUNK * DI * 4);
  // split-K partials alias the delta..hin region (dead at their use time):
  //  part2 (3 MB)  live GEMM2->reduce2, before gemm3_fused writes delta
  //  part4 (32 MB) live GEMM4->reduce4, after scan3 is done with delta/hend/hin
  float* part2 = delta;
  float* part4 = delta;

  hipMemcpyAsync(x, x_in, (size_t)MROWS * DM * 4, hipMemcpyDeviceToDevice, stream);

  convert_all_kernel<<<2048, 256, 0, stream>>>(W_in, Win_bf, W_x, Wx_bf,
                                               W_dt, Wdt_bf, W_out, Wout_bf);

  for (int l = 0; l < NL; l++) {
    const unsigned short* Win_l  = Win_bf  + (size_t)l * 2 * DI * DM;
    const unsigned short* Wx_l   = Wx_bf   + (size_t)l * 96 * DI;
    const unsigned short* Wdt_l  = Wdt_bf  + (size_t)l * DI * RK;
    const unsigned short* Wout_l = Wout_bf + (size_t)l * DM * DI;

    rmsnorm_kernel<<<MROWS, 256, 0, stream>>>(x, norm_w + (size_t)l * DM, h_bf);

    // GEMM1: xz = h @ W_in^T   [2048, 4096], K=1024  -> bf16
    gemm_bt<128, 128, 2, 2, 0><<<dim3(MROWS / 128, (2 * DI) / 128), 256, 0, stream>>>(
        h_bf, Win_l, xz_bf, nullptr, MROWS, 2 * DI, DM, 2 * DI, 1);

    conv_silu_kernel<<<(BATCH * LSEQ * DI) / 256, 256, 0, stream>>>(
        xz_bf, conv_w + (size_t)l * DI * 4, conv_b + (size_t)l * DI, xc_bf);

    // GEMM2: dbc = xc @ W_x^T  [2048, 96], K=2048, split-K=4 -> partials
    gemm_bt<64, 96, 4, 1, 4><<<dim3(MROWS / 64, 1, 4), 256, 0, stream>>>(
        xc_bf, Wx_l, part2, nullptr, MROWS, 96, DI, 96, 4);
    reduce2_kernel<<<(MROWS * 96) / 256, 256, 0, stream>>>(part2, dbc);

    // GEMM3 (fused VALU kernel): delta = softplus(dbc[:, :64] @ W_dt^T + b_dt)
    gemm3_fused<<<dim3(MROWS / G3R, DI / G3C), 256, 0, stream>>>(
        dbc, Wdt_l, b_dt + (size_t)l * DI, delta);

    // selective scan (chunked 3-phase)
    scan1_kernel<<<dim3(DI / 256, NCHUNK, BATCH), 256, 0, stream>>>(
        delta, xc_bf, dbc, A_log + (size_t)l * DI * NS, hend, sumd);
    scan2_kernel<<<(BATCH * DI) / 256, 256, 0, stream>>>(
        A_log + (size_t)l * DI * NS, hend, sumd, hin);
    scan3_kernel<<<dim3(DI / 256, NCHUNK, BATCH), 256, 0, stream>>>(
        delta, xc_bf, dbc, A_log + (size_t)l * DI * NS, hin, Dv + (size_t)l * DI, xz_bf, g_bf);

    // GEMM4: split-K=4 partials of (y*silu(z)) @ W_out^T, then x += sum(parts)
    gemm_bt<128, 128, 2, 2, 4><<<dim3(MROWS / 128, DM / 128, 4), 256, 0, stream>>>(
        g_bf, Wout_l, part4, nullptr, MROWS, DM, DI, DM, 4);
    reduce4_kernel<<<(MROWS * DM) / 1024, 256, 0, stream>>>(part4, x);
  }
}

// Round 5
// 844.377 us; speedup vs baseline: 1.1357x; 1.0084x over previous
//
#include <hip/hip_runtime.h>
#include <hip/hip_bf16.h>
#include <math.h>

#define NL 4
#define DM 1024
#define DI 2048
#define RK 64
#define NS 16
#define LSEQ 1024
#define BATCH 2
#define MROWS (BATCH*LSEQ)   // 2048 rows for all GEMMs
#define NCHUNK 32
#define LC 32                // LSEQ / NCHUNK

typedef __attribute__((ext_vector_type(8))) short bf16x8;
typedef __attribute__((ext_vector_type(4))) float f32x4;

__device__ __forceinline__ float bf2f(unsigned short u){
  union { unsigned int i; float f; } v; v.i = ((unsigned int)u) << 16; return v.f;
}
__device__ __forceinline__ unsigned short f2bf(float f){
  union { float f; unsigned int i; } v; v.f = f;
  unsigned int r = v.i + 0x7fffu + ((v.i >> 16) & 1u);  // RNE
  return (unsigned short)(r >> 16);
}
__device__ __forceinline__ float sigmoidf_(float x){ return 1.0f / (1.0f + __expf(-x)); }

// async 16B/lane global->LDS DMA (lds dest = wave-uniform base + lane*16)
__device__ __forceinline__ void gl2lds16(const void* g, void* l) {
  __builtin_amdgcn_global_load_lds((__attribute__((address_space(1))) void*)g,
                                   (__attribute__((address_space(3))) void*)l,
                                   16, 0, 0);
}

// ---------------------------------------------------------------------------
// bf16 MFMA GEMM:  C[m,n] = sum_k A[m,k] * W[n,k]
// A row-major [M,K] bf16, W row-major [N,K] bf16 (B^T layout).
// 64x128 tile (6 blocks/CU at 24 KB LDS -> 24 waves/CU for latency hiding),
// BK=64, global_load_lds staging with XOR bank-swizzle:
//   LDS 16B-unit j of tile row r holds global col-unit (j ^ (r&7)).
// EPI: 0 = store bf16; 4 = store fp32 partial at slice blockIdx.z (split-K)
// ---------------------------------------------------------------------------
template<int BM, int BN, int WAVES_M, int WAVES_N, int EPI>
__global__ __launch_bounds__(256)
void gemm_bt(const unsigned short* __restrict__ A, const unsigned short* __restrict__ W,
             void* __restrict__ C, int M, int N, int K, int ldc, int kslices)
{
  constexpr int MT = BM / (WAVES_M * 16);
  constexpr int NT = BN / (WAVES_N * 16);
  __shared__ __align__(16) unsigned short As[BM * 64];
  __shared__ __align__(16) unsigned short Bs[BN * 64];

  const int tid  = threadIdx.x;
  const int wave = tid >> 6;
  const int lane = tid & 63;
  const int wm   = wave / WAVES_N;
  const int wn   = wave % WAVES_N;
  const int quad = lane >> 4;
  const int l16  = lane & 15;
  const int srow = lane >> 3;               // row within 8-row staging chunk
  const int scol = ((lane & 7) ^ srow) * 8; // swizzled global col (bf16)

  const int m0 = blockIdx.x * BM;
  const int n0 = blockIdx.y * BN;
  const int Ks = K / kslices;
  const int kb = blockIdx.z * Ks;

  f32x4 acc[MT][NT];
  #pragma unroll
  for (int i = 0; i < MT; i++)
    #pragma unroll
    for (int j = 0; j < NT; j++)
      acc[i][j] = (f32x4){0.f, 0.f, 0.f, 0.f};

  for (int k0 = kb; k0 < kb + Ks; k0 += 64) {
    const unsigned short* Ab = A + (size_t)m0 * K + k0;
    #pragma unroll
    for (int i = 0; i < BM / 32; i++) {
      int c = i * 4 + wave;
      gl2lds16(Ab + (size_t)(c * 8 + srow) * K + scol, As + c * 512);
    }
    const unsigned short* Wb = W + (size_t)n0 * K + k0;
    #pragma unroll
    for (int i = 0; i < BN / 32; i++) {
      int c = i * 4 + wave;
      gl2lds16(Wb + (size_t)(c * 8 + srow) * K + scol, Bs + c * 512);
    }
    __syncthreads();

    #pragma unroll
    for (int h = 0; h < 2; h++) {
      bf16x8 af[MT], bfr[NT];
      #pragma unroll
      for (int mt = 0; mt < MT; mt++) {
        int rA = wm * MT * 16 + mt * 16 + l16;
        af[mt] = *(const bf16x8*)(As + rA * 64 + (((h * 4 + quad) ^ (rA & 7)) << 3));
      }
      #pragma unroll
      for (int nt = 0; nt < NT; nt++) {
        int rB = wn * NT * 16 + nt * 16 + l16;
        bfr[nt] = *(const bf16x8*)(Bs + rB * 64 + (((h * 4 + quad) ^ (rB & 7)) << 3));
      }
      #pragma unroll
      for (int mt = 0; mt < MT; mt++)
        #pragma unroll
        for (int nt = 0; nt < NT; nt++)
          acc[mt][nt] = __builtin_amdgcn_mfma_f32_16x16x32_bf16(af[mt], bfr[nt], acc[mt][nt], 0, 0, 0);
    }
    __syncthreads();
  }

  // epilogue: D[m][n] with m = quad*4 + r, n = l16 (verified gfx950 C/D layout)
  const size_t slice_off = (size_t)blockIdx.z * M * ldc;
  #pragma unroll
  for (int mt = 0; mt < MT; mt++) {
    #pragma unroll
    for (int nt = 0; nt < NT; nt++) {
      int n = n0 + wn * NT * 16 + nt * 16 + l16;
      #pragma unroll
      for (int r = 0; r < 4; r++) {
        int m = m0 + wm * MT * 16 + mt * 16 + quad * 4 + r;
        float v = acc[mt][nt][r];
        size_t off = (size_t)m * ldc + n;
        if constexpr (EPI == 0)      ((unsigned short*)C)[off] = f2bf(v);
        else                         ((float*)C)[slice_off + off] = v;
      }
    }
  }
}

// ---------------------------------------------------------------------------
// GEMM3 (K=64, 0.5 GFLOP -> pure VALU):
//   delta[m, c] = softplus( dot(dbc[m, 0:64], Wdt[c, 0:64]) + b_dt[c] )   [bf16 out]
// ---------------------------------------------------------------------------
#define G3R 8
#define G3C 256
#define G3P 264   // padded LDS row stride (shorts)
__global__ __launch_bounds__(256)
void gemm3_fused(const float* __restrict__ dbc, const unsigned short* __restrict__ Wdt,
                 const float* __restrict__ b_dt, unsigned short* __restrict__ delta)
{
  __shared__ float dts[G3R][RK];                       // 2 KB
  __shared__ __align__(16) unsigned short Ws[RK][G3P]; // ~33 KB, [k][col]
  const int tid = threadIdx.x;
  const int m0 = blockIdx.x * G3R;
  const int c0 = blockIdx.y * G3C;

  { // stage dbc rows (first 64 cols of the 96-col rows)
    int r = tid >> 5, k = (tid & 31) * 2;
    float2 v = *(const float2*)(dbc + (size_t)(m0 + r) * 96 + k);
    dts[r][k] = v.x; dts[r][k + 1] = v.y;
  }
  { // stage Wdt[c0+tid][0:64] transposed into Ws[k][tid]
    const unsigned short* wrow = Wdt + (size_t)(c0 + tid) * RK;
    #pragma unroll
    for (int ch = 0; ch < 8; ch++) {
      union { bf16x8 v; unsigned short u[8]; } w;
      w.v = *(const bf16x8*)(wrow + ch * 8);
      #pragma unroll
      for (int j = 0; j < 8; j++) Ws[ch * 8 + j][tid] = w.u[j];
    }
  }
  __syncthreads();

  const int r  = tid >> 5;       // row within block
  const int cg = tid & 31;       // 8-col group
  float acc[8] = {0.f, 0.f, 0.f, 0.f, 0.f, 0.f, 0.f, 0.f};
  #pragma unroll 4
  for (int k = 0; k < RK; k++) {
    float a = dts[r][k];
    union { bf16x8 v; unsigned short u[8]; } w;
    w.v = *(const bf16x8*)&Ws[k][cg * 8];
    #pragma unroll
    for (int j = 0; j < 8; j++) acc[j] += a * bf2f(w.u[j]);
  }

  const int m = m0 + r, c = c0 + cg * 8;
  float4 b0 = *(const float4*)(b_dt + c);
  float4 b1 = *(const float4*)(b_dt + c + 4);
  float bb[8] = {b0.x, b0.y, b0.z, b0.w, b1.x, b1.y, b1.z, b1.w};
  union { unsigned short u[8]; uint4 v; } o;
  #pragma unroll
  for (int j = 0; j < 8; j++) {
    float v = acc[j] + bb[j];
    o.u[j] = f2bf((v > 15.0f) ? v : __logf(1.0f + __expf(v)));
  }
  *(uint4*)(delta + (size_t)m * DI + c) = o.v;
}

// x += sum of 2 split-K partials (GEMM4 epilogue)
__global__ __launch_bounds__(256)
void reduce4_kernel(const float* __restrict__ part, float* __restrict__ x)
{
  const size_t MN = (size_t)MROWS * DM;
  int i = blockIdx.x * 256 + threadIdx.x;
  float4 a = ((const float4*)part)[i];
  float4 b = ((const float4*)(part + MN))[i];
  float4 o = ((float4*)x)[i];
  o.x += a.x + b.x;
  o.y += a.y + b.y;
  o.z += a.z + b.z;
  o.w += a.w + b.w;
  ((float4*)x)[i] = o;
}

// dbc = sum of 4 split-K partials
__global__ __launch_bounds__(256)
void reduce2_kernel(const float* __restrict__ part, float* __restrict__ dbc)
{
  const int MN = MROWS * 96;
  int i = blockIdx.x * 256 + threadIdx.x;
  dbc[i] = part[i] + part[MN + i] + part[2 * MN + i] + part[3 * MN + i];
}

// ---------------------------------------------------------------------------
__global__ __launch_bounds__(256)
void rmsnorm_kernel(const float* __restrict__ x, const float* __restrict__ w,
                    unsigned short* __restrict__ h)
{
  const int row = blockIdx.x;
  const float4 a = ((const float4*)(x + (size_t)row * DM))[threadIdx.x];
  float ss = a.x*a.x + a.y*a.y + a.z*a.z + a.w*a.w;
  #pragma unroll
  for (int o = 32; o > 0; o >>= 1) ss += __shfl_down(ss, o);
  __shared__ float red[4];
  if ((threadIdx.x & 63) == 0) red[threadIdx.x >> 6] = ss;
  __syncthreads();
  float rs = rsqrtf((red[0] + red[1] + red[2] + red[3]) * (1.0f / DM) + 1e-5f);
  const float4 wv = ((const float4*)w)[threadIdx.x];
  ushort4 o4;
  o4.x = f2bf(a.x * rs * wv.x);
  o4.y = f2bf(a.y * rs * wv.y);
  o4.z = f2bf(a.z * rs * wv.z);
  o4.w = f2bf(a.w * rs * wv.w);
  ((ushort4*)(h + (size_t)row * DM))[threadIdx.x] = o4;
}

// causal depthwise conv (width 4) + SiLU ; xi = xz[..., :DI]
__global__ __launch_bounds__(256)
void conv_silu_kernel(const unsigned short* __restrict__ xz,
                      const float* __restrict__ cw, const float* __restrict__ cb,
                      unsigned short* __restrict__ xc)
{
  int idx = blockIdx.x * 256 + threadIdx.x;        // [B, L, DI]
  int d = idx & (DI - 1);
  int t = (idx >> 11) & (LSEQ - 1);
  int b = idx >> 21;
  const float4 w4 = ((const float4*)cw)[d];
  const float wk[4] = {w4.x, w4.y, w4.z, w4.w};
  const unsigned short* xi = xz + (size_t)b * LSEQ * (2 * DI) + d;
  float acc = cb[d];
  #pragma unroll
  for (int k = 0; k < 4; k++) {
    int tt = t - 3 + k;
    if (tt >= 0) acc += bf2f(xi[(size_t)tt * (2 * DI)]) * wk[k];
  }
  xc[idx] = f2bf(acc * sigmoidf_(acc));
}

// one-shot fused fp32->bf16 conversion of all weights (segmented grid-stride,
// 16B stores). Segment element offsets (all /8): W_in | W_x | W_dt | W_out
#define SEG0 (NL*2*DI*DM)                 // 16777216
#define SEG1 (SEG0 + NL*96*DI)            // 17563648
#define SEG2 (SEG1 + NL*DI*RK)            // 18087936
#define SEG3 (SEG2 + NL*DM*DI)            // 26476544
__global__ void convert_all_kernel(const float* __restrict__ W_in, unsigned short* __restrict__ Win_bf,
                                   const float* __restrict__ W_x,  unsigned short* __restrict__ Wx_bf,
                                   const float* __restrict__ W_dt, unsigned short* __restrict__ Wdt_bf,
                                   const float* __restrict__ W_out,unsigned short* __restrict__ Wout_bf)
{
  const int T8 = SEG3 / 8;
  int stride = gridDim.x * 256;
  for (int i = blockIdx.x * 256 + threadIdx.x; i < T8; i += stride) {
    int e = i * 8;
    const float* s; unsigned short* d; int off;
    if (e < SEG0)      { s = W_in;  d = Win_bf;  off = e; }
    else if (e < SEG1) { s = W_x;   d = Wx_bf;   off = e - SEG0; }
    else if (e < SEG2) { s = W_dt;  d = Wdt_bf;  off = e - SEG1; }
    else               { s = W_out; d = Wout_bf; off = e - SEG2; }
    float4 a = *(const float4*)(s + off);
    float4 b = *(const float4*)(s + off + 4);
    union { unsigned short u[8]; uint4 v; } o;
    o.u[0] = f2bf(a.x); o.u[1] = f2bf(a.y); o.u[2] = f2bf(a.z); o.u[3] = f2bf(a.w);
    o.u[4] = f2bf(b.x); o.u[5] = f2bf(b.y); o.u[6] = f2bf(b.z); o.u[7] = f2bf(b.w);
    *(uint4*)(d + off) = o.v;
  }
}

// ---------------------------------------------------------------------------
// Chunked selective scan.  State layout for hend/hin: [b][chunk][n][d] (coalesced in d)
// ---------------------------------------------------------------------------
__global__ __launch_bounds__(256)
void scan1_kernel(const unsigned short* __restrict__ delta, const unsigned short* __restrict__ xc,
                  const float* __restrict__ dbc, const float* __restrict__ A_log,
                  float* __restrict__ hend, float* __restrict__ sumd)
{
  const int d = blockIdx.x * 256 + threadIdx.x;
  const int c = blockIdx.y;
  const int b = blockIdx.z;
  const int t0 = c * LC;
  __shared__ float bc[LC][32];                     // cols 0..15 = B, 16..31 = C
  #pragma unroll
  for (int i = 0; i < (LC * 32) / 256; i++) {
    int f = i * 256 + threadIdx.x;
    int r = f >> 5, col = f & 31;
    bc[r][col] = dbc[(size_t)(b * LSEQ + t0 + r) * 96 + 64 + col];
  }
  float Av[NS], h[NS];
  #pragma unroll
  for (int n = 0; n < NS; n++) { Av[n] = -__expf(A_log[(size_t)d * NS + n]); h[n] = 0.f; }
  __syncthreads();
  float sd = 0.f;
  for (int t = 0; t < LC; t++) {
    size_t ix = (size_t)(b * LSEQ + t0 + t) * DI + d;
    float dt = bf2f(delta[ix]);
    float xcv = bf2f(xc[ix]);
    sd += dt;
    float dx = dt * xcv;
    #pragma unroll
    for (int n = 0; n < NS; n++) {
      float da = __expf(dt * Av[n]);
      h[n] = da * h[n] + dx * bc[t][n];
    }
  }
  size_t base = ((size_t)(b * NCHUNK + c) * NS) * DI + d;
  #pragma unroll
  for (int n = 0; n < NS; n++) hend[base + (size_t)n * DI] = h[n];
  sumd[(size_t)(b * NCHUNK + c) * DI + d] = sd;
}

__global__ __launch_bounds__(256)
void scan2_kernel(const float* __restrict__ A_log, const float* __restrict__ hend,
                  const float* __restrict__ sumd, float* __restrict__ hin)
{
  int g = blockIdx.x * 256 + threadIdx.x;          // BATCH*DI threads
  int b = g >> 11;
  int d = g & (DI - 1);
  float Av[NS], H[NS];
  #pragma unroll
  for (int n = 0; n < NS; n++) { Av[n] = -__expf(A_log[(size_t)d * NS + n]); H[n] = 0.f; }
  for (int c = 0; c < NCHUNK; c++) {
    size_t base = ((size_t)(b * NCHUNK + c) * NS) * DI + d;
    float sd = sumd[(size_t)(b * NCHUNK + c) * DI + d];
    #pragma unroll
    for (int n = 0; n < NS; n++) {
      hin[base + (size_t)n * DI] = H[n];
      float da = __expf(Av[n] * sd);
      H[n] = da * H[n] + hend[base + (size_t)n * DI];
    }
  }
}

__global__ __launch_bounds__(256)
void scan3_kernel(const unsigned short* __restrict__ delta, const unsigned short* __restrict__ xc,
                  const float* __restrict__ dbc, const float* __restrict__ A_log,
                  const float* __restrict__ hin, const float* __restrict__ Dvec,
                  const unsigned short* __restrict__ xz, unsigned short* __restrict__ g)
{
  const int d = blockIdx.x * 256 + threadIdx.x;
  const int c = blockIdx.y;
  const int b = blockIdx.z;
  const int t0 = c * LC;
  __shared__ float bc[LC][32];
  #pragma unroll
  for (int i = 0; i < (LC * 32) / 256; i++) {
    int f = i * 256 + threadIdx.x;
    int r = f >> 5, col = f & 31;
    bc[r][col] = dbc[(size_t)(b * LSEQ + t0 + r) * 96 + 64 + col];
  }
  float Av[NS], h[NS];
  size_t base = ((size_t)(b * NCHUNK + c) * NS) * DI + d;
  #pragma unroll
  for (int n = 0; n < NS; n++) {
    Av[n] = -__expf(A_log[(size_t)d * NS + n]);
    h[n] = hin[base + (size_t)n * DI];
  }
  const float Dd = Dvec[d];
  __syncthreads();
  for (int t = 0; t < LC; t++) {
    size_t ix = (size_t)(b * LSEQ + t0 + t) * DI + d;
    float dt = bf2f(delta[ix]);
    float xcv = bf2f(xc[ix]);
    float dx = dt * xcv;
    float y = Dd * xcv;
    #pragma unroll
    for (int n = 0; n < NS; n++) {
      float da = __expf(dt * Av[n]);
      h[n] = da * h[n] + dx * bc[t][n];
      y += h[n] * bc[t][16 + n];
    }
    float zv = bf2f(xz[(size_t)(b * LSEQ + t0 + t) * (2 * DI) + DI + d]);
    g[ix] = f2bf(y * (zv * sigmoidf_(zv)));
  }
}

// ---------------------------------------------------------------------------
extern "C" void kernel_launch(void* const* d_in, const int* in_sizes, int n_in,
                              void* d_out, int out_size, void* d_ws, size_t ws_size,
                              hipStream_t stream)
{
  const float* x_in   = (const float*)d_in[0];
  const float* norm_w = (const float*)d_in[1];
  const float* W_in   = (const float*)d_in[2];
  const float* conv_w = (const float*)d_in[3];
  const float* conv_b = (const float*)d_in[4];
  const float* W_x    = (const float*)d_in[5];
  const float* W_dt   = (const float*)d_in[6];
  const float* b_dt   = (const float*)d_in[7];
  const float* A_log  = (const float*)d_in[8];
  const float* Dv     = (const float*)d_in[9];
  const float* W_out  = (const float*)d_in[10];
  float* x = (float*)d_out;                        // running residual stream

  char* p = (char*)d_ws;
  auto alloc = [&](size_t bytes) {
    void* r = (void*)p;
    p += (bytes + 255) & ~(size_t)255;
    return r;
  };
  unsigned short* Win_bf  = (unsigned short*)alloc((size_t)NL * 2 * DI * DM * 2);
  unsigned short* Wx_bf   = (unsigned short*)alloc((size_t)NL * 96 * DI * 2);
  unsigned short* Wdt_bf  = (unsigned short*)alloc((size_t)NL * DI * RK * 2);
  unsigned short* Wout_bf = (unsigned short*)alloc((size_t)NL * DM * DI * 2);
  unsigned short* h_bf    = (unsigned short*)alloc((size_t)MROWS * DM * 2);
  unsigned short* xz_bf   = (unsigned short*)alloc((size_t)MROWS * 2 * DI * 2);
  unsigned short* xc_bf   = (unsigned short*)alloc((size_t)MROWS * DI * 2);
  float*          dbc     = (float*)alloc((size_t)MROWS * 96 * 4);
  unsigned short* g_bf    = (unsigned short*)alloc((size_t)MROWS * DI * 2);
  unsigned short* delta   = (unsigned short*)alloc((size_t)MROWS * DI * 2);  // bf16
  float*          hend    = (float*)alloc((size_t)BATCH * NCHUNK * NS * DI * 4);
  float*          hin     = (float*)alloc((size_t)BATCH * NCHUNK * NS * DI * 4);
  float*          sumd    = (float*)alloc((size_t)BATCH * NCHUNK * DI * 4);
  // split-K partials alias hend+hin (16.8 MB contiguous, dead at their use time):
  //  part2 (3.1 MB) live GEMM2->reduce2, before scan1 writes hend
  //  part4 (16.8 MB = exactly hend+hin) live GEMM4->reduce4, after scan3
  float* part2 = hend;
  float* part4 = hend;

  hipMemcpyAsync(x, x_in, (size_t)MROWS * DM * 4, hipMemcpyDeviceToDevice, stream);

  convert_all_kernel<<<2048, 256, 0, stream>>>(W_in, Win_bf, W_x, Wx_bf,
                                               W_dt, Wdt_bf, W_out, Wout_bf);

  for (int l = 0; l < NL; l++) {
    const unsigned short* Win_l  = Win_bf  + (size_t)l * 2 * DI * DM;
    const unsigned short* Wx_l   = Wx_bf   + (size_t)l * 96 * DI;
    const unsigned short* Wdt_l  = Wdt_bf  + (size_t)l * DI * RK;
    const unsigned short* Wout_l = Wout_bf + (size_t)l * DM * DI;

    rmsnorm_kernel<<<MROWS, 256, 0, stream>>>(x, norm_w + (size_t)l * DM, h_bf);

    // GEMM1: xz = h @ W_in^T   [2048, 4096], K=1024  -> bf16  (1024 blocks)
    gemm_bt<64, 128, 2, 2, 0><<<dim3(MROWS / 64, (2 * DI) / 128), 256, 0, stream>>>(
        h_bf, Win_l, xz_bf, MROWS, 2 * DI, DM, 2 * DI, 1);

    conv_silu_kernel<<<(BATCH * LSEQ * DI) / 256, 256, 0, stream>>>(
        xz_bf, conv_w + (size_t)l * DI * 4, conv_b + (size_t)l * DI, xc_bf);

    // GEMM2: dbc = xc @ W_x^T  [2048, 96], K=2048, split-K=4 -> partials
    gemm_bt<64, 96, 4, 1, 4><<<dim3(MROWS / 64, 1, 4), 256, 0, stream>>>(
        xc_bf, Wx_l, part2, MROWS, 96, DI, 96, 4);
    reduce2_kernel<<<(MROWS * 96) / 256, 256, 0, stream>>>(part2, dbc);

    // GEMM3 (fused VALU): delta = softplus(dbc[:, :64] @ W_dt^T + b_dt) -> bf16
    gemm3_fused<<<dim3(MROWS / G3R, DI / G3C), 256, 0, stream>>>(
        dbc, Wdt_l, b_dt + (size_t)l * DI, delta);

    // selective scan (chunked 3-phase)
    scan1_kernel<<<dim3(DI / 256, NCHUNK, BATCH), 256, 0, stream>>>(
        delta, xc_bf, dbc, A_log + (size_t)l * DI * NS, hend, sumd);
    scan2_kernel<<<(BATCH * DI) / 256, 256, 0, stream>>>(
        A_log + (size_t)l * DI * NS, hend, sumd, hin);
    scan3_kernel<<<dim3(DI / 256, NCHUNK, BATCH), 256, 0, stream>>>(
        delta, xc_bf, dbc, A_log + (size_t)l * DI * NS, hin, Dv + (size_t)l * DI, xz_bf, g_bf);

    // GEMM4: split-K=2 partials of (y*silu(z)) @ W_out^T, then x += sum(parts)
    gemm_bt<64, 128, 2, 2, 4><<<dim3(MROWS / 64, DM / 128, 2), 256, 0, stream>>>(
        g_bf, Wout_l, part4, MROWS, DM, DI, DM, 2);
    reduce4_kernel<<<(MROWS * DM) / 1024, 256, 0, stream>>>(part4, x);
  }
}